// Round 10
// baseline (162.269 us; speedup 1.0000x reference)
//
#include <hip/hip_runtime.h>
#include <hip/hip_bf16.h>

// Spectral attention: B=2, N=50000, D=256, H=8, Dh=32, K_EIG=32, NUM_BANDS=3
// Key identity: Qf = E^T (x Wq^T + bq) = (E^T x) Wq^T + s * bq, s[k] = sum_n E[n,k]
// N-sized work: U = E^T x (read x once) and out = E @ out_freq (write out once).
// Lessons: r2 arrays spill; r3 no redundant HBM reads; r4 >=4 blocks/CU;
// r5 stage E in LDS; r6 deep prefetch; r7 waves own disjoint rows;
// r8 NEVER set launch_bounds min-waves on reg-heavy kernels (spill = WRITE_SIZE blowup);
// r9 LDS *instruction count* is a per-CU shared-pipe floor: broadcast b128 ~12cy,
//    so maximize FMA per ds_read (lane owns d-QUAD, split k across waves).

constexpr int D = 256;   // d_model

// ---------------------------------------------------------------- k_colsum
__global__ __launch_bounds__(256) void k_colsum(const float* __restrict__ E,
                                                float* __restrict__ pS, int N) {
  int k = threadIdx.x & 31;
  int rg = threadIdx.x >> 5;
  int rs = (N + 255) >> 8;
  int n0 = blockIdx.x * rs;
  int n1 = n0 + rs; if (n1 > N) n1 = N;
  float acc = 0.f;
  for (int n = n0 + rg; n < n1; n += 8) acc += E[(size_t)n * 32 + k];
  __shared__ float red[256];
  red[threadIdx.x] = acc;
  __syncthreads();
  if (threadIdx.x < 32) {
    float t = red[threadIdx.x];
#pragma unroll
    for (int i = 1; i < 8; ++i) t += red[i * 32 + threadIdx.x];
    pS[blockIdx.x * 32 + threadIdx.x] = t;
  }
}

// ---------------------------------------------------------------- k_partial
// grid = B*nchunk. Wave w: kh = w&1 (k-half 16 k's), rp = w>>1 (row parity).
// Lane owns d-quad (float4 x, 16B/lane, full 256 d per wave). Per wave-row:
// 4 broadcast ds_read_b128 + 64 FMA (4x the FMA:LDS ratio of r9).
// 2-way cross-wave reduce (rp pairs) -> pU[bc][32][256].
__global__ __launch_bounds__(256) void k_partial(const float* __restrict__ x,
                                                 const float* __restrict__ E,
                                                 float* __restrict__ pU,
                                                 int N, int nchunk, int rpc) {
  int bc = blockIdx.x;                     // b*nchunk + c
  int c = bc % nchunk;
  int b = bc / nchunk;
  int t = threadIdx.x;
  int w = t >> 6;
  int kh = w & 1;                          // k-half: k in [16*kh, 16*kh+16)
  int rp = w >> 1;                         // row parity: rows rp, rp+2, ...
  int lane = t & 63;
  int n0 = c * rpc;
  int n1 = n0 + rpc; if (n1 > N) n1 = N;
  int nrows = n1 - n0; if (nrows < 0) nrows = 0;

  // 32KB: E tile (rpc<=256 rows x 32 f) first, then 16KB reduce buf (reused)
  __shared__ __align__(16) float smem[8192];

  if (nrows > 0) {  // stage E tile [nrows][32]
    const float4* Esrc = reinterpret_cast<const float4*>(E + (size_t)n0 * 32);
    float4* Edst = reinterpret_cast<float4*>(smem);
    int nf4 = nrows * 8;
    for (int i = t; i < nf4; i += 256) Edst[i] = Esrc[i];
  }
  __syncthreads();

  float4 a0={0,0,0,0},a1={0,0,0,0},a2={0,0,0,0},a3={0,0,0,0};
  float4 a4={0,0,0,0},a5={0,0,0,0},a6={0,0,0,0},a7={0,0,0,0};
  float4 a8={0,0,0,0},a9={0,0,0,0},a10={0,0,0,0},a11={0,0,0,0};
  float4 a12={0,0,0,0},a13={0,0,0,0},a14={0,0,0,0},a15={0,0,0,0};

  int mrows = (nrows > rp) ? ((nrows - rp + 1) >> 1) : 0;

  if (mrows > 0) {
    const float* xb = x + (size_t)b * N * D + 4 * lane;
#define XLD(j) (*reinterpret_cast<const float4*>( \
    xb + (size_t)(n0 + rp + 2 * ((j) < mrows ? (j) : mrows - 1)) * D))

    float4 p0 = XLD(0), p1 = XLD(1), p2 = XLD(2), p3 = XLD(3);
    float4 p4 = XLD(4), p5 = XLD(5), p6 = XLD(6), p7 = XLD(7);

#define FK(s, A) { A.x = fmaf(s, xq.x, A.x); A.y = fmaf(s, xq.y, A.y); \
                   A.z = fmaf(s, xq.z, A.z); A.w = fmaf(s, xq.w, A.w); }
#define ROWP(j, q) {                                               \
    const float4* eb = reinterpret_cast<const float4*>(            \
        smem + (rp + 2 * (j)) * 32 + kh * 16);                     \
    float4 e0 = eb[0], e1 = eb[1], e2 = eb[2], e3 = eb[3];         \
    float4 xq = q;                                                 \
    FK(e0.x, a0)  FK(e0.y, a1)  FK(e0.z, a2)  FK(e0.w, a3)         \
    FK(e1.x, a4)  FK(e1.y, a5)  FK(e1.z, a6)  FK(e1.w, a7)         \
    FK(e2.x, a8)  FK(e2.y, a9)  FK(e2.z, a10) FK(e2.w, a11)        \
    FK(e3.x, a12) FK(e3.y, a13) FK(e3.z, a14) FK(e3.w, a15) }

    int j = 0;
#pragma unroll 1
    for (; j + 8 <= mrows; j += 8) {
      ROWP(j + 0, p0) ROWP(j + 1, p1) ROWP(j + 2, p2) ROWP(j + 3, p3)
      p0 = XLD(j + 8);  p1 = XLD(j + 9);  p2 = XLD(j + 10); p3 = XLD(j + 11);
      ROWP(j + 4, p4) ROWP(j + 5, p5) ROWP(j + 6, p6) ROWP(j + 7, p7)
      p4 = XLD(j + 12); p5 = XLD(j + 13); p6 = XLD(j + 14); p7 = XLD(j + 15);
    }
    int rem = mrows - j;
    if (rem > 0) ROWP(j + 0, p0)
    if (rem > 1) ROWP(j + 1, p1)
    if (rem > 2) ROWP(j + 2, p2)
    if (rem > 3) ROWP(j + 3, p3)
    if (rem > 4) ROWP(j + 4, p4)
    if (rem > 5) ROWP(j + 5, p5)
    if (rem > 6) ROWP(j + 6, p6)
#undef ROWP
#undef FK
#undef XLD
  }

  // 2-way cross-wave reduce: rp=1 wave stages 8 k's, rp=0 wave adds + stores.
  // buf[kh][kp][lane] float4 = 2*8*64*16B = 16KB (reuses E tile space).
  float4* buf = reinterpret_cast<float4*>(smem);
  float* ob = pU + (size_t)bc * 8192 + (size_t)(kh * 16) * 256 + 4 * lane;

#define REDP(koff, A0, A1, A2, A3, A4, A5, A6, A7)                 \
  __syncthreads();                                                 \
  if (rp == 1) {                                                   \
    buf[(kh * 8 + 0) * 64 + lane] = A0;                            \
    buf[(kh * 8 + 1) * 64 + lane] = A1;                            \
    buf[(kh * 8 + 2) * 64 + lane] = A2;                            \
    buf[(kh * 8 + 3) * 64 + lane] = A3;                            \
    buf[(kh * 8 + 4) * 64 + lane] = A4;                            \
    buf[(kh * 8 + 5) * 64 + lane] = A5;                            \
    buf[(kh * 8 + 6) * 64 + lane] = A6;                            \
    buf[(kh * 8 + 7) * 64 + lane] = A7;                            \
  }                                                                \
  __syncthreads();                                                 \
  if (rp == 0) {                                                   \
    float4 s;                                                      \
    s = buf[(kh*8+0)*64+lane]; A0.x+=s.x; A0.y+=s.y; A0.z+=s.z; A0.w+=s.w; \
    *reinterpret_cast<float4*>(ob + ((koff)+0)*256) = A0;          \
    s = buf[(kh*8+1)*64+lane]; A1.x+=s.x; A1.y+=s.y; A1.z+=s.z; A1.w+=s.w; \
    *reinterpret_cast<float4*>(ob + ((koff)+1)*256) = A1;          \
    s = buf[(kh*8+2)*64+lane]; A2.x+=s.x; A2.y+=s.y; A2.z+=s.z; A2.w+=s.w; \
    *reinterpret_cast<float4*>(ob + ((koff)+2)*256) = A2;          \
    s = buf[(kh*8+3)*64+lane]; A3.x+=s.x; A3.y+=s.y; A3.z+=s.z; A3.w+=s.w; \
    *reinterpret_cast<float4*>(ob + ((koff)+3)*256) = A3;          \
    s = buf[(kh*8+4)*64+lane]; A4.x+=s.x; A4.y+=s.y; A4.z+=s.z; A4.w+=s.w; \
    *reinterpret_cast<float4*>(ob + ((koff)+4)*256) = A4;          \
    s = buf[(kh*8+5)*64+lane]; A5.x+=s.x; A5.y+=s.y; A5.z+=s.z; A5.w+=s.w; \
    *reinterpret_cast<float4*>(ob + ((koff)+5)*256) = A5;          \
    s = buf[(kh*8+6)*64+lane]; A6.x+=s.x; A6.y+=s.y; A6.z+=s.z; A6.w+=s.w; \
    *reinterpret_cast<float4*>(ob + ((koff)+6)*256) = A6;          \
    s = buf[(kh*8+7)*64+lane]; A7.x+=s.x; A7.y+=s.y; A7.z+=s.z; A7.w+=s.w; \
    *reinterpret_cast<float4*>(ob + ((koff)+7)*256) = A7;          \
  }

  REDP(0, a0, a1, a2, a3, a4, a5, a6, a7)
  REDP(8, a8, a9, a10, a11, a12, a13, a14, a15)
#undef REDP
}

// ---------------------------------------------------------------- k_reduce
// U[b,kd] = sum_c pU[b][c][kd]; 512 blocks, 8 subs x 8 indep accumulators.
__global__ __launch_bounds__(256) void k_reduce(const float* __restrict__ pU,
                                                float* __restrict__ U, int nchunk) {
  int e = blockIdx.x * 32 + (threadIdx.x & 31);
  int sub = threadIdx.x >> 5;              // 0..7
  int b = e >> 13;
  int kd = e & 8191;
  const float* p = pU + (size_t)b * nchunk * 8192 + kd;
  float a0 = 0.f, a1 = 0.f, a2 = 0.f, a3 = 0.f;
  float a4 = 0.f, a5 = 0.f, a6 = 0.f, a7 = 0.f;
  int c = sub;
#pragma unroll 1
  for (; c + 56 < nchunk; c += 64) {
    a0 += p[(size_t)c * 8192];
    a1 += p[(size_t)(c + 8) * 8192];
    a2 += p[(size_t)(c + 16) * 8192];
    a3 += p[(size_t)(c + 24) * 8192];
    a4 += p[(size_t)(c + 32) * 8192];
    a5 += p[(size_t)(c + 40) * 8192];
    a6 += p[(size_t)(c + 48) * 8192];
    a7 += p[(size_t)(c + 56) * 8192];
  }
  for (; c < nchunk; c += 8) a0 += p[(size_t)c * 8192];
  __shared__ float red[256];
  red[threadIdx.x] = ((a0 + a1) + (a2 + a3)) + ((a4 + a5) + (a6 + a7));
  __syncthreads();
  if (threadIdx.x < 32) {
    float s = red[threadIdx.x];
#pragma unroll
    for (int i = 1; i < 8; ++i) s += red[i * 32 + threadIdx.x];
    U[e] = s;
  }
}

// ---------------------------------------------------------------- k_project
__global__ __launch_bounds__(256) void k_project(
    const float* __restrict__ U, const float* __restrict__ pS,
    const float* __restrict__ Wq, const float* __restrict__ bq,
    const float* __restrict__ Wk, const float* __restrict__ bk,
    const float* __restrict__ Wv, const float* __restrict__ bv,
    const float* __restrict__ ev, const float* __restrict__ bb,
    const float* __restrict__ fw,
    float* __restrict__ Qfg, float* __restrict__ Kfg, float* __restrict__ Vfg) {
  int blk = blockIdx.x;                    // b*32 + k
  int k = blk & 31;
  int t = threadIdx.x;
  __shared__ __align__(16) float u[256];
  __shared__ float red[256];
  u[t] = U[(size_t)blk * 256 + t];
  red[t] = pS[t * 32 + k];
  __syncthreads();
#pragma unroll
  for (int off = 128; off > 0; off >>= 1) {
    if (t < off) red[t] += red[t + off];
    __syncthreads();
  }
  float sk = red[0];

  // filter response — FP64 to match numpy ref branch semantics
  float mnf = ev[0], mxf = ev[0];
#pragma unroll
  for (int i = 1; i < 32; ++i) { float v = ev[i]; mnf = fminf(mnf, v); mxf = fmaxf(mxf, v); }
  double mn = (double)mnf, mx = (double)mxf;
  double lam = ((double)ev[k] - mn) / (mx - mn + 1e-8);
  int h = t >> 5;
  float g = 0.f;
#pragma unroll
  for (int i = 0; i < 3; ++i) {
    double lo = (double)bb[h * 4 + i], hi = (double)bb[h * 4 + i + 1];
    if (lam >= lo && lam < hi) g = fw[(h * 3 + i) * 32 + k];
  }

  const float4* u4 = reinterpret_cast<const float4*>(u);
  const float4* wq4 = reinterpret_cast<const float4*>(Wq) + (size_t)t * 64;
  const float4* wk4 = reinterpret_cast<const float4*>(Wk) + (size_t)t * 64;
  const float4* wv4 = reinterpret_cast<const float4*>(Wv) + (size_t)t * 64;
  float aq = 0.f, ak = 0.f, av = 0.f;
#pragma unroll 4
  for (int j = 0; j < 64; ++j) {
    float4 uv = u4[j];
    float4 q = wq4[j], kk = wk4[j], vv = wv4[j];
    aq = fmaf(uv.x, q.x, aq);  aq = fmaf(uv.y, q.y, aq);
    aq = fmaf(uv.z, q.z, aq);  aq = fmaf(uv.w, q.w, aq);
    ak = fmaf(uv.x, kk.x, ak); ak = fmaf(uv.y, kk.y, ak);
    ak = fmaf(uv.z, kk.z, ak); ak = fmaf(uv.w, kk.w, ak);
    av = fmaf(uv.x, vv.x, av); av = fmaf(uv.y, vv.y, av);
    av = fmaf(uv.z, vv.z, av); av = fmaf(uv.w, vv.w, av);
  }
  Qfg[(size_t)blk * 256 + t] = (aq + bq[t] * sk) * g;
  Kfg[(size_t)blk * 256 + t] = (ak + bk[t] * sk) * g;
  Vfg[(size_t)blk * 256 + t] = (av + bv[t] * sk) * g;
}

// ---------------------------------------------------------------- k_attn
__global__ __launch_bounds__(1024) void k_attn(const float* __restrict__ Qfg,
                                               const float* __restrict__ Kfg,
                                               const float* __restrict__ Vfg,
                                               float* __restrict__ of) {
  int blk = blockIdx.x;                    // b*8 + h
  int b = blk >> 3, h = blk & 7;
  int tid = threadIdx.x;
  int row = tid >> 5, col = tid & 31;
  __shared__ float Q[32][33], Kt[32][33], V[32][33], A[32][33];
  size_t base = (size_t)b * 32 * 256 + h * 32;
  Q[row][col]  = Qfg[base + row * 256 + col];
  Kt[row][col] = Kfg[base + row * 256 + col];
  V[row][col]  = Vfg[base + row * 256 + col];
  __syncthreads();
  float sc = 0.f;
#pragma unroll
  for (int d0 = 0; d0 < 32; ++d0) sc = fmaf(Q[row][d0], Kt[col][d0], sc);
  sc *= 0.17677669529663687f;              // 1/sqrt(32)
  float m = sc;
#pragma unroll
  for (int o = 16; o > 0; o >>= 1) m = fmaxf(m, __shfl_xor(m, o, 32));
  float p = expf(sc - m);
  float su = p;
#pragma unroll
  for (int o = 16; o > 0; o >>= 1) su += __shfl_xor(su, o, 32);
  A[row][col] = p / su;
  __syncthreads();
  float o_ = 0.f;
#pragma unroll
  for (int l = 0; l < 32; ++l) o_ = fmaf(A[row][l], V[l][col], o_);
  of[base + row * 256 + col] = o_;
}

// ---------------------------------------------------------------- k_expand
// out[b,n,d] = sum_k E[n,k] * of[b,k,d]. Wave w: bb = w&1 (batch), rp = w>>1
// (row parity). Lane owns d-quad -> float4 stores (1KB/wave-inst), of in 32
// float4 regs, split-k accumulator pair. Per wave-row: 8 b128 + 128 FMA.
__global__ __launch_bounds__(256) void k_expand(const float* __restrict__ E,
                                                const float* __restrict__ of,
                                                float* __restrict__ out,
                                                int N, int rows) {
  int n0 = blockIdx.x * rows;
  int n1 = n0 + rows; if (n1 > N) n1 = N;
  int nrows = n1 - n0;
  if (nrows <= 0) return;
  int t = threadIdx.x;
  int w = t >> 6;
  int bb = w & 1;                          // batch
  int rp = w >> 1;                         // row parity
  int lane = t & 63;

  const float* ofb = of + (size_t)bb * 8192 + 4 * lane;
#define LDF(i) float4 f##i = *reinterpret_cast<const float4*>(ofb + (i) * 256);
  LDF(0)  LDF(1)  LDF(2)  LDF(3)  LDF(4)  LDF(5)  LDF(6)  LDF(7)
  LDF(8)  LDF(9)  LDF(10) LDF(11) LDF(12) LDF(13) LDF(14) LDF(15)
  LDF(16) LDF(17) LDF(18) LDF(19) LDF(20) LDF(21) LDF(22) LDF(23)
  LDF(24) LDF(25) LDF(26) LDF(27) LDF(28) LDF(29) LDF(30) LDF(31)
#undef LDF

  __shared__ __align__(16) float Elds[64 * 32];    // rows <= 64
  {
    const float4* Esrc = reinterpret_cast<const float4*>(E + (size_t)n0 * 32);
    float4* Edst = reinterpret_cast<float4*>(Elds);
    int nf4 = nrows * 8;
    for (int i = t; i < nf4; i += 256) Edst[i] = Esrc[i];
  }
  __syncthreads();

  float* ob = out + (size_t)bb * N * D + 4 * lane;

#define EX(s, fk, A) { A.x = fmaf(s, fk.x, A.x); A.y = fmaf(s, fk.y, A.y); \
                       A.z = fmaf(s, fk.z, A.z); A.w = fmaf(s, fk.w, A.w); }
#pragma unroll 1
  for (int i = rp; i < nrows; i += 2) {
    const float4* er = reinterpret_cast<const float4*>(Elds + i * 32);
    float4 e0 = er[0], e1 = er[1], e2 = er[2], e3 = er[3];
    float4 e4 = er[4], e5 = er[5], e6 = er[6], e7 = er[7];
    float4 oA = {0.f, 0.f, 0.f, 0.f}, oB = {0.f, 0.f, 0.f, 0.f};
    EX(e0.x, f0,  oA) EX(e0.y, f1,  oB) EX(e0.z, f2,  oA) EX(e0.w, f3,  oB)
    EX(e1.x, f4,  oA) EX(e1.y, f5,  oB) EX(e1.z, f6,  oA) EX(e1.w, f7,  oB)
    EX(e2.x, f8,  oA) EX(e2.y, f9,  oB) EX(e2.z, f10, oA) EX(e2.w, f11, oB)
    EX(e3.x, f12, oA) EX(e3.y, f13, oB) EX(e3.z, f14, oA) EX(e3.w, f15, oB)
    EX(e4.x, f16, oA) EX(e4.y, f17, oB) EX(e4.z, f18, oA) EX(e4.w, f19, oB)
    EX(e5.x, f20, oA) EX(e5.y, f21, oB) EX(e5.z, f22, oA) EX(e5.w, f23, oB)
    EX(e6.x, f24, oA) EX(e6.y, f25, oB) EX(e6.z, f26, oA) EX(e6.w, f27, oB)
    EX(e7.x, f28, oA) EX(e7.y, f29, oB) EX(e7.z, f30, oA) EX(e7.w, f31, oB)
    float4 o4;
    o4.x = oA.x + oB.x; o4.y = oA.y + oB.y;
    o4.z = oA.z + oB.z; o4.w = oA.w + oB.w;
    *reinterpret_cast<float4*>(ob + (size_t)(n0 + i) * D) = o4;
  }
#undef EX
}

// ---------------------------------------------------------------- launch
extern "C" void kernel_launch(void* const* d_in, const int* in_sizes, int n_in,
                              void* d_out, int out_size, void* d_ws, size_t ws_size,
                              hipStream_t stream) {
  const float* x  = (const float*)d_in[0];
  const float* E  = (const float*)d_in[1];
  const float* ev = (const float*)d_in[2];
  const float* Wq = (const float*)d_in[3];
  const float* bq = (const float*)d_in[4];
  const float* Wk = (const float*)d_in[5];
  const float* bk = (const float*)d_in[6];
  const float* Wv = (const float*)d_in[7];
  const float* bv = (const float*)d_in[8];
  const float* bb = (const float*)d_in[9];
  const float* fw = (const float*)d_in[10];
  float* out = (float*)d_out;
  float* ws  = (float*)d_ws;

  const int N = in_sizes[1] / 32;          // 50000
  const int B = in_sizes[0] / (N * 256);   // 2

  // workspace layout (floats)
  float* U   = ws;                         // B*32*256 = 16384
  float* Qfg = ws + 16384;
  float* Kfg = ws + 32768;
  float* Vfg = ws + 49152;
  float* of  = ws + 65536;
  float* pS  = ws + 81920;                 // 256*32 = 8192
  float* pU  = ws + 90112;                 // B*nchunk*8192 floats

  // nchunk = 512 -> grid 1024 (4 blocks/CU), pU 33.6 MB (fit since r6).
  // Fallback 256 (rpc=196 <= 256 rows, fits the 32KB smem tile).
  int nchunk = 512;
  if ((90112 + (size_t)B * nchunk * 8192) * sizeof(float) > ws_size) nchunk = 256;
  int rpc = (N + nchunk - 1) / nchunk;

  k_colsum<<<256, 256, 0, stream>>>(E, pS, N);
  k_partial<<<B * nchunk, 256, 0, stream>>>(x, E, pU, N, nchunk, rpc);
  k_reduce<<<B * 8192 / 32, 256, 0, stream>>>(pU, U, nchunk);
  k_project<<<B * 32, 256, 0, stream>>>(U, pS, Wq, bq, Wk, bk, Wv, bv,
                                        ev, bb, fw, Qfg, Kfg, Vfg);
  k_attn<<<B * 8, 1024, 0, stream>>>(Qfg, Kfg, Vfg, of);
  int rows = 64;
  int nbr = (N + rows - 1) / rows;
  k_expand<<<nbr, 256, 0, stream>>>(E, of, out, N, rows);
}

// Round 11
// 150.638 us; speedup vs baseline: 1.0772x; 1.0772x over previous
//
#include <hip/hip_runtime.h>
#include <hip/hip_bf16.h>

// Spectral attention: B=2, N=50000, D=256, H=8, Dh=32, K_EIG=32, NUM_BANDS=3
// Key identity: Qf = E^T (x Wq^T + bq) = (E^T x) Wq^T + s * bq, s[k] = sum_n E[n,k]
// N-sized work: U = E^T x (read x once) and out = E @ out_freq (write out once).
// Lessons: r2 arrays spill (named regs only); r3 no redundant HBM x reads;
// r4 >=4 blocks/CU; r6 deep prefetch; r7 waves own disjoint x rows;
// r8 never set launch_bounds min-waves (spill shows as WRITE_SIZE blowup);
// r9 LDS instr count is a shared per-CU pipe floor; r10 E is L1/L2-resident
// (FETCH 4MB) -> LDS staging of E is pure overhead; read E via uniform loads
// (1 transaction, broadcast) and keep VGPR <= ~128 for 4 waves/SIMD.

constexpr int D = 256;   // d_model

// ---------------------------------------------------------------- k_colsum
__global__ __launch_bounds__(256) void k_colsum(const float* __restrict__ E,
                                                float* __restrict__ pS, int N) {
  int k = threadIdx.x & 31;
  int rg = threadIdx.x >> 5;
  int rs = (N + 255) >> 8;
  int n0 = blockIdx.x * rs;
  int n1 = n0 + rs; if (n1 > N) n1 = N;
  float acc = 0.f;
  for (int n = n0 + rg; n < n1; n += 8) acc += E[(size_t)n * 32 + k];
  __shared__ float red[256];
  red[threadIdx.x] = acc;
  __syncthreads();
  if (threadIdx.x < 32) {
    float t = red[threadIdx.x];
#pragma unroll
    for (int i = 1; i < 8; ++i) t += red[i * 32 + threadIdx.x];
    pS[blockIdx.x * 32 + threadIdx.x] = t;
  }
}

// ---------------------------------------------------------------- k_partial
// grid = B*nchunk, 128 threads = 2 waves; wave = d-half (disjoint x!), lane
// owns d-pair. All 32 k in 32 named float2 accs (64 VGPR). E rows read via
// uniform float4 loads (L1-hot broadcast, no LDS). 8-deep x prefetch.
// pU[bc][k][d] = sum_{n in chunk} E[n,k] * x[b,n,d]; no cross-wave reduce.
__global__ __launch_bounds__(128) void k_partial(const float* __restrict__ x,
                                                 const float* __restrict__ E,
                                                 float* __restrict__ pU,
                                                 int N, int nchunk, int rpc) {
  int bc = blockIdx.x;                     // b*nchunk + c
  int c = bc % nchunk;
  int b = bc / nchunk;
  int t = threadIdx.x;
  int dh = t >> 6;                         // wave = d-half 0/1
  int lane = t & 63;
  int n0 = c * rpc;
  int n1 = n0 + rpc; if (n1 > N) n1 = N;
  int nrows = n1 - n0; if (nrows < 0) nrows = 0;

  float2 a0={0,0},a1={0,0},a2={0,0},a3={0,0},a4={0,0},a5={0,0},a6={0,0},a7={0,0};
  float2 a8={0,0},a9={0,0},a10={0,0},a11={0,0},a12={0,0},a13={0,0},a14={0,0},a15={0,0};
  float2 a16={0,0},a17={0,0},a18={0,0},a19={0,0},a20={0,0},a21={0,0},a22={0,0},a23={0,0};
  float2 a24={0,0},a25={0,0},a26={0,0},a27={0,0},a28={0,0},a29={0,0},a30={0,0},a31={0,0};

  if (nrows > 0) {
    const float* xb = x + (size_t)b * N * D + dh * 128 + 2 * lane;
#define XLD(j) (*reinterpret_cast<const float2*>( \
    xb + (size_t)(n0 + ((j) < nrows ? (j) : nrows - 1)) * D))

    float2 p0 = XLD(0), p1 = XLD(1), p2 = XLD(2), p3 = XLD(3);
    float2 p4 = XLD(4), p5 = XLD(5), p6 = XLD(6), p7 = XLD(7);

#define FK2(s, A) { A.x = fmaf(s, xq.x, A.x); A.y = fmaf(s, xq.y, A.y); }
#define ROW(j, q) {                                                \
    const float4* Er = reinterpret_cast<const float4*>(            \
        E + (size_t)(n0 + (j)) * 32);                              \
    float4 e0 = Er[0], e1 = Er[1], e2 = Er[2], e3 = Er[3];         \
    float4 e4 = Er[4], e5 = Er[5], e6 = Er[6], e7 = Er[7];         \
    float2 xq = q;                                                 \
    FK2(e0.x, a0)  FK2(e0.y, a1)  FK2(e0.z, a2)  FK2(e0.w, a3)     \
    FK2(e1.x, a4)  FK2(e1.y, a5)  FK2(e1.z, a6)  FK2(e1.w, a7)     \
    FK2(e2.x, a8)  FK2(e2.y, a9)  FK2(e2.z, a10) FK2(e2.w, a11)    \
    FK2(e3.x, a12) FK2(e3.y, a13) FK2(e3.z, a14) FK2(e3.w, a15)    \
    FK2(e4.x, a16) FK2(e4.y, a17) FK2(e4.z, a18) FK2(e4.w, a19)    \
    FK2(e5.x, a20) FK2(e5.y, a21) FK2(e5.z, a22) FK2(e5.w, a23)    \
    FK2(e6.x, a24) FK2(e6.y, a25) FK2(e6.z, a26) FK2(e6.w, a27)    \
    FK2(e7.x, a28) FK2(e7.y, a29) FK2(e7.z, a30) FK2(e7.w, a31) }

    int j = 0;
#pragma unroll 1
    for (; j + 8 <= nrows; j += 8) {
      ROW(j + 0, p0) ROW(j + 1, p1) ROW(j + 2, p2) ROW(j + 3, p3)
      p0 = XLD(j + 8);  p1 = XLD(j + 9);  p2 = XLD(j + 10); p3 = XLD(j + 11);
      ROW(j + 4, p4) ROW(j + 5, p5) ROW(j + 6, p6) ROW(j + 7, p7)
      p4 = XLD(j + 12); p5 = XLD(j + 13); p6 = XLD(j + 14); p7 = XLD(j + 15);
    }
    int rem = nrows - j;                   // 0..7, rows j..j+rem-1 in p0..p6
    if (rem > 0) ROW(j + 0, p0)
    if (rem > 1) ROW(j + 1, p1)
    if (rem > 2) ROW(j + 2, p2)
    if (rem > 3) ROW(j + 3, p3)
    if (rem > 4) ROW(j + 4, p4)
    if (rem > 5) ROW(j + 5, p5)
    if (rem > 6) ROW(j + 6, p6)
#undef ROW
#undef FK2
#undef XLD
  }

  float* o = pU + (size_t)bc * 8192 + dh * 128 + 2 * lane;
#define STO(k, A) *reinterpret_cast<float2*>(o + (k) * 256) = A;
  STO(0, a0)   STO(1, a1)   STO(2, a2)   STO(3, a3)
  STO(4, a4)   STO(5, a5)   STO(6, a6)   STO(7, a7)
  STO(8, a8)   STO(9, a9)   STO(10, a10) STO(11, a11)
  STO(12, a12) STO(13, a13) STO(14, a14) STO(15, a15)
  STO(16, a16) STO(17, a17) STO(18, a18) STO(19, a19)
  STO(20, a20) STO(21, a21) STO(22, a22) STO(23, a23)
  STO(24, a24) STO(25, a25) STO(26, a26) STO(27, a27)
  STO(28, a28) STO(29, a29) STO(30, a30) STO(31, a31)
#undef STO
}

// ---------------------------------------------------------------- k_reduce
// U[b,kd] = sum_c pU[b][c][kd]; 512 blocks, 8 subs x 8 indep accumulators.
__global__ __launch_bounds__(256) void k_reduce(const float* __restrict__ pU,
                                                float* __restrict__ U, int nchunk) {
  int e = blockIdx.x * 32 + (threadIdx.x & 31);
  int sub = threadIdx.x >> 5;              // 0..7
  int b = e >> 13;
  int kd = e & 8191;
  const float* p = pU + (size_t)b * nchunk * 8192 + kd;
  float a0 = 0.f, a1 = 0.f, a2 = 0.f, a3 = 0.f;
  float a4 = 0.f, a5 = 0.f, a6 = 0.f, a7 = 0.f;
  int c = sub;
#pragma unroll 1
  for (; c + 56 < nchunk; c += 64) {
    a0 += p[(size_t)c * 8192];
    a1 += p[(size_t)(c + 8) * 8192];
    a2 += p[(size_t)(c + 16) * 8192];
    a3 += p[(size_t)(c + 24) * 8192];
    a4 += p[(size_t)(c + 32) * 8192];
    a5 += p[(size_t)(c + 40) * 8192];
    a6 += p[(size_t)(c + 48) * 8192];
    a7 += p[(size_t)(c + 56) * 8192];
  }
  for (; c < nchunk; c += 8) a0 += p[(size_t)c * 8192];
  __shared__ float red[256];
  red[threadIdx.x] = ((a0 + a1) + (a2 + a3)) + ((a4 + a5) + (a6 + a7));
  __syncthreads();
  if (threadIdx.x < 32) {
    float s = red[threadIdx.x];
#pragma unroll
    for (int i = 1; i < 8; ++i) s += red[i * 32 + threadIdx.x];
    U[e] = s;
  }
}

// ---------------------------------------------------------------- k_project
__global__ __launch_bounds__(256) void k_project(
    const float* __restrict__ U, const float* __restrict__ pS,
    const float* __restrict__ Wq, const float* __restrict__ bq,
    const float* __restrict__ Wk, const float* __restrict__ bk,
    const float* __restrict__ Wv, const float* __restrict__ bv,
    const float* __restrict__ ev, const float* __restrict__ bb,
    const float* __restrict__ fw,
    float* __restrict__ Qfg, float* __restrict__ Kfg, float* __restrict__ Vfg) {
  int blk = blockIdx.x;                    // b*32 + k
  int k = blk & 31;
  int t = threadIdx.x;
  __shared__ __align__(16) float u[256];
  __shared__ float red[256];
  u[t] = U[(size_t)blk * 256 + t];
  red[t] = pS[t * 32 + k];
  __syncthreads();
#pragma unroll
  for (int off = 128; off > 0; off >>= 1) {
    if (t < off) red[t] += red[t + off];
    __syncthreads();
  }
  float sk = red[0];

  // filter response — FP64 to match numpy ref branch semantics
  float mnf = ev[0], mxf = ev[0];
#pragma unroll
  for (int i = 1; i < 32; ++i) { float v = ev[i]; mnf = fminf(mnf, v); mxf = fmaxf(mxf, v); }
  double mn = (double)mnf, mx = (double)mxf;
  double lam = ((double)ev[k] - mn) / (mx - mn + 1e-8);
  int h = t >> 5;
  float g = 0.f;
#pragma unroll
  for (int i = 0; i < 3; ++i) {
    double lo = (double)bb[h * 4 + i], hi = (double)bb[h * 4 + i + 1];
    if (lam >= lo && lam < hi) g = fw[(h * 3 + i) * 32 + k];
  }

  const float4* u4 = reinterpret_cast<const float4*>(u);
  const float4* wq4 = reinterpret_cast<const float4*>(Wq) + (size_t)t * 64;
  const float4* wk4 = reinterpret_cast<const float4*>(Wk) + (size_t)t * 64;
  const float4* wv4 = reinterpret_cast<const float4*>(Wv) + (size_t)t * 64;
  float aq = 0.f, ak = 0.f, av = 0.f;
#pragma unroll 4
  for (int j = 0; j < 64; ++j) {
    float4 uv = u4[j];
    float4 q = wq4[j], kk = wk4[j], vv = wv4[j];
    aq = fmaf(uv.x, q.x, aq);  aq = fmaf(uv.y, q.y, aq);
    aq = fmaf(uv.z, q.z, aq);  aq = fmaf(uv.w, q.w, aq);
    ak = fmaf(uv.x, kk.x, ak); ak = fmaf(uv.y, kk.y, ak);
    ak = fmaf(uv.z, kk.z, ak); ak = fmaf(uv.w, kk.w, ak);
    av = fmaf(uv.x, vv.x, av); av = fmaf(uv.y, vv.y, av);
    av = fmaf(uv.z, vv.z, av); av = fmaf(uv.w, vv.w, av);
  }
  Qfg[(size_t)blk * 256 + t] = (aq + bq[t] * sk) * g;
  Kfg[(size_t)blk * 256 + t] = (ak + bk[t] * sk) * g;
  Vfg[(size_t)blk * 256 + t] = (av + bv[t] * sk) * g;
}

// ---------------------------------------------------------------- k_attn
__global__ __launch_bounds__(1024) void k_attn(const float* __restrict__ Qfg,
                                               const float* __restrict__ Kfg,
                                               const float* __restrict__ Vfg,
                                               float* __restrict__ of) {
  int blk = blockIdx.x;                    // b*8 + h
  int b = blk >> 3, h = blk & 7;
  int tid = threadIdx.x;
  int row = tid >> 5, col = tid & 31;
  __shared__ float Q[32][33], Kt[32][33], V[32][33], A[32][33];
  size_t base = (size_t)b * 32 * 256 + h * 32;
  Q[row][col]  = Qfg[base + row * 256 + col];
  Kt[row][col] = Kfg[base + row * 256 + col];
  V[row][col]  = Vfg[base + row * 256 + col];
  __syncthreads();
  float sc = 0.f;
#pragma unroll
  for (int d0 = 0; d0 < 32; ++d0) sc = fmaf(Q[row][d0], Kt[col][d0], sc);
  sc *= 0.17677669529663687f;              // 1/sqrt(32)
  float m = sc;
#pragma unroll
  for (int o = 16; o > 0; o >>= 1) m = fmaxf(m, __shfl_xor(m, o, 32));
  float p = expf(sc - m);
  float su = p;
#pragma unroll
  for (int o = 16; o > 0; o >>= 1) su += __shfl_xor(su, o, 32);
  A[row][col] = p / su;
  __syncthreads();
  float o_ = 0.f;
#pragma unroll
  for (int l = 0; l < 32; ++l) o_ = fmaf(A[row][l], V[l][col], o_);
  of[base + row * 256 + col] = o_;
}

// ---------------------------------------------------------------- k_expand
// out[b,n,d] = sum_k E[n,k] * of[b,k,d]. 256 thr = 4 waves (bb = w&1 batch,
// dh = w>>1 d-half); lane owns d-pair. of in 32 float2 regs (64 VGPR); E rows
// via uniform float4 loads (L1-hot broadcast, no LDS). float2 stores.
__global__ __launch_bounds__(256) void k_expand(const float* __restrict__ E,
                                                const float* __restrict__ of,
                                                float* __restrict__ out,
                                                int N, int rows) {
  int n0 = blockIdx.x * rows;
  int n1 = n0 + rows; if (n1 > N) n1 = N;
  if (n1 <= n0) return;
  int t = threadIdx.x;
  int w = t >> 6;
  int bb = w & 1;                          // batch
  int dh = w >> 1;                         // d-half
  int lane = t & 63;

  const float* ofb = of + (size_t)bb * 8192 + dh * 128 + 2 * lane;
#define LDF(i) float2 f##i = *reinterpret_cast<const float2*>(ofb + (i) * 256);
  LDF(0)  LDF(1)  LDF(2)  LDF(3)  LDF(4)  LDF(5)  LDF(6)  LDF(7)
  LDF(8)  LDF(9)  LDF(10) LDF(11) LDF(12) LDF(13) LDF(14) LDF(15)
  LDF(16) LDF(17) LDF(18) LDF(19) LDF(20) LDF(21) LDF(22) LDF(23)
  LDF(24) LDF(25) LDF(26) LDF(27) LDF(28) LDF(29) LDF(30) LDF(31)
#undef LDF

  float* ob = out + (size_t)bb * N * D + dh * 128 + 2 * lane;

#define EX(s, fk, A) { A.x = fmaf(s, fk.x, A.x); A.y = fmaf(s, fk.y, A.y); }
#pragma unroll 1
  for (int n = n0; n < n1; ++n) {
    const float4* Er = reinterpret_cast<const float4*>(E + (size_t)n * 32);
    float4 e0 = Er[0], e1 = Er[1], e2 = Er[2], e3 = Er[3];
    float4 e4 = Er[4], e5 = Er[5], e6 = Er[6], e7 = Er[7];
    float2 oA = {0.f, 0.f}, oB = {0.f, 0.f};
    EX(e0.x, f0,  oA) EX(e0.y, f1,  oB) EX(e0.z, f2,  oA) EX(e0.w, f3,  oB)
    EX(e1.x, f4,  oA) EX(e1.y, f5,  oB) EX(e1.z, f6,  oA) EX(e1.w, f7,  oB)
    EX(e2.x, f8,  oA) EX(e2.y, f9,  oB) EX(e2.z, f10, oA) EX(e2.w, f11, oB)
    EX(e3.x, f12, oA) EX(e3.y, f13, oB) EX(e3.z, f14, oA) EX(e3.w, f15, oB)
    EX(e4.x, f16, oA) EX(e4.y, f17, oB) EX(e4.z, f18, oA) EX(e4.w, f19, oB)
    EX(e5.x, f20, oA) EX(e5.y, f21, oB) EX(e5.z, f22, oA) EX(e5.w, f23, oB)
    EX(e6.x, f24, oA) EX(e6.y, f25, oB) EX(e6.z, f26, oA) EX(e6.w, f27, oB)
    EX(e7.x, f28, oA) EX(e7.y, f29, oB) EX(e7.z, f30, oA) EX(e7.w, f31, oB)
    float2 o2;
    o2.x = oA.x + oB.x;
    o2.y = oA.y + oB.y;
    *reinterpret_cast<float2*>(ob + (size_t)n * D) = o2;
  }
#undef EX
}

// ---------------------------------------------------------------- launch
extern "C" void kernel_launch(void* const* d_in, const int* in_sizes, int n_in,
                              void* d_out, int out_size, void* d_ws, size_t ws_size,
                              hipStream_t stream) {
  const float* x  = (const float*)d_in[0];
  const float* E  = (const float*)d_in[1];
  const float* ev = (const float*)d_in[2];
  const float* Wq = (const float*)d_in[3];
  const float* bq = (const float*)d_in[4];
  const float* Wk = (const float*)d_in[5];
  const float* bk = (const float*)d_in[6];
  const float* Wv = (const float*)d_in[7];
  const float* bv = (const float*)d_in[8];
  const float* bb = (const float*)d_in[9];
  const float* fw = (const float*)d_in[10];
  float* out = (float*)d_out;
  float* ws  = (float*)d_ws;

  const int N = in_sizes[1] / 32;          // 50000
  const int B = in_sizes[0] / (N * 256);   // 2

  // workspace layout (floats)
  float* U   = ws;                         // B*32*256 = 16384
  float* Qfg = ws + 16384;
  float* Kfg = ws + 32768;
  float* Vfg = ws + 49152;
  float* of  = ws + 65536;
  float* pS  = ws + 81920;                 // 256*32 = 8192
  float* pU  = ws + 90112;                 // B*nchunk*8192 floats

  // nchunk = 512 -> grid 1024 (all co-resident), pU 33.6 MB (fit since r6).
  int nchunk = 512;
  if ((90112 + (size_t)B * nchunk * 8192) * sizeof(float) > ws_size) nchunk = 256;
  int rpc = (N + nchunk - 1) / nchunk;

  k_colsum<<<256, 256, 0, stream>>>(E, pS, N);
  k_partial<<<B * nchunk, 128, 0, stream>>>(x, E, pU, N, nchunk, rpc);
  k_reduce<<<B * 8192 / 32, 256, 0, stream>>>(pU, U, nchunk);
  k_project<<<B * 32, 256, 0, stream>>>(U, pS, Wq, bq, Wk, bk, Wv, bv,
                                        ev, bb, fw, Qfg, Kfg, Vfg);
  k_attn<<<B * 8, 1024, 0, stream>>>(Qfg, Kfg, Vfg, of);
  int rows = 50;
  int nbr = (N + rows - 1) / rows;
  k_expand<<<nbr, 256, 0, stream>>>(E, of, out, N, rows);
}